// Round 3
// baseline (231.489 us; speedup 1.0000x reference)
//
#include <hip/hip_runtime.h>
#include <math.h>

// Problem constants (reference: P=256, T=65536, UNITS=128, WIDTH=1.0)
#define Pn 256
#define Tn 65536
#define Un 128
#define NC 256          // number of t-chunks
#define CHUNK 256       // Tn / NC
#define ST 32           // GEMM sub-tile depth inside a chunk

typedef float f4 __attribute__((ext_vector_type(4)));

// ---------------------------------------------------------------------------
// Kernel A: per-(row, chunk) composed clamp operator (A,B).
// Play step:  s' = min(max(s, x), x+1)  with x = w*input.
// compose(old=(A1,B1), then new=(A2,B2)): A=max(A1,A2); B=min(max(B1,A2),B2).
// Block = 1024 threads = 4 quarter-scanners x 256 rows, combined via LDS.
// ---------------------------------------------------------------------------
__global__ __launch_bounds__(1024) void kA(const float* __restrict__ in,
                                           const float* __restrict__ pw,
                                           float* __restrict__ Aarr,
                                           float* __restrict__ Barr) {
  __shared__ float As[4][Pn], Bs[4][Pn];
  const int c = blockIdx.x, tid = threadIdx.x;
  const int q = tid >> 8, p = tid & 255;
  const float w = pw[p];
  const f4* src = (const f4*)(in + (size_t)p * Tn + c * CHUNK + q * 64);
  float A = -3.402823466e38f, B = 3.402823466e38f;  // identity operator
#pragma unroll
  for (int i = 0; i < 16; ++i) {
    f4 v = src[i];
#pragma unroll
    for (int j = 0; j < 4; ++j) {
      float x = v[j] * w;
      A = fmaxf(A, x);
      B = fminf(fmaxf(B, x), x + 1.0f);
    }
  }
  As[q][p] = A;
  Bs[q][p] = B;
  __syncthreads();
  if (tid < Pn) {
    float Ac = As[0][tid], Bc = Bs[0][tid];
#pragma unroll
    for (int qq = 1; qq < 4; ++qq) {
      float a2 = As[qq][tid], b2 = Bs[qq][tid];
      Bc = fminf(fmaxf(Bc, a2), b2);
      Ac = fmaxf(Ac, a2);
    }
    Aarr[c * Pn + tid] = Ac;
    Barr[c * Pn + tid] = Bc;
  }
}

// ---------------------------------------------------------------------------
// Kernel B: per-row sequential scan over the NC chunk operators.
// Stores the INCOMING state of each chunk: sinb[c][p]. 1 block, 256 threads.
// ---------------------------------------------------------------------------
__global__ __launch_bounds__(256) void kB(const float* __restrict__ Aarr,
                                          const float* __restrict__ Barr,
                                          const float* __restrict__ st,
                                          float* __restrict__ sinb) {
  const int p = threadIdx.x;
  float s = st[p];
  for (int c = 0; c < NC; ++c) {
    sinb[c * Pn + p] = s;
    s = fminf(fmaxf(s, Aarr[c * Pn + p]), Barr[c * Pn + p]);
  }
}

// ---------------------------------------------------------------------------
// Kernel C: rescan chunk with correct incoming state + fused f32 GEMM.
// Block = 256 threads, one chunk (256 t) per block.
//   Scan role : thread p scans its row, writes post-update s into sS[t][p].
//   GEMM role : thread (pg=tid>>3, ug=tid&7) owns 8 p-rows x 16 u-cols.
// Epilogue: per-chunk partial [c][p][u] to ws (or atomicAdd into d_out).
// ---------------------------------------------------------------------------
template <bool ATOMIC>
__global__ __launch_bounds__(256, 1) void kC(const float* __restrict__ in,
                                             const float* __restrict__ pw,
                                             const float* __restrict__ Kg,
                                             const float* __restrict__ sinb,
                                             float* __restrict__ outp) {
  __shared__ float sS[ST][Pn];   // 32 KB, post-update states, t-major
  __shared__ float sK[ST][Un];   // 16 KB, K tile
  const int c = blockIdx.x, tid = threadIdx.x;

  // scan role
  const float w = pw[tid];
  float s = sinb[c * Pn + tid];
  const f4* src = (const f4*)(in + (size_t)tid * Tn + c * CHUNK);

  // gemm role
  const int ug = tid & 7, pg = tid >> 3;
  const int p0 = pg * 8;
  float acc[8][16];
#pragma unroll
  for (int a = 0; a < 8; ++a)
#pragma unroll
    for (int b = 0; b < 16; ++b) acc[a][b] = 0.0f;

  const f4* Kt = (const f4*)(Kg + (size_t)c * CHUNK * Un);

  for (int sub = 0; sub < CHUNK / ST; ++sub) {
    // stage K tile rows [sub*ST, sub*ST+ST): 1024 f4 / 256 threads = 4 each
#pragma unroll
    for (int k = 0; k < 4; ++k) {
      int idx = k * 256 + tid;
      int r = idx >> 5, col = idx & 31;       // 32 f4 per row
      *(f4*)&sK[r][col * 4] = Kt[(size_t)(sub * ST + r) * (Un / 4) + col];
    }
    // scan ST elements of own row, write post-update states
#pragma unroll
    for (int i4 = 0; i4 < ST / 4; ++i4) {
      f4 v = src[sub * (ST / 4) + i4];
#pragma unroll
      for (int j = 0; j < 4; ++j) {
        float x = v[j] * w;
        s = fminf(fmaxf(s, x), x + 1.0f);     // min LAST (degenerate A>B ok)
        sS[i4 * 4 + j][tid] = s;
      }
    }
    __syncthreads();
    // register-blocked GEMM: [256p x ST] x [ST x 128u]
#pragma unroll 2
    for (int i = 0; i < ST; ++i) {
      f4 sv0 = *(const f4*)&sS[i][p0];
      f4 sv1 = *(const f4*)&sS[i][p0 + 4];
      f4 kv0 = *(const f4*)&sK[i][ug * 4];
      f4 kv1 = *(const f4*)&sK[i][32 + ug * 4];
      f4 kv2 = *(const f4*)&sK[i][64 + ug * 4];
      f4 kv3 = *(const f4*)&sK[i][96 + ug * 4];
#pragma unroll
      for (int a = 0; a < 8; ++a) {
        float sa = (a < 4) ? sv0[a] : sv1[a - 4];
#pragma unroll
        for (int l = 0; l < 4; ++l) {
          acc[a][0 + l]  += sa * kv0[l];
          acc[a][4 + l]  += sa * kv1[l];
          acc[a][8 + l]  += sa * kv2[l];
          acc[a][12 + l] += sa * kv3[l];
        }
      }
    }
    __syncthreads();
  }

  if (ATOMIC) {
#pragma unroll
    for (int a = 0; a < 8; ++a)
#pragma unroll
      for (int k = 0; k < 4; ++k)
#pragma unroll
        for (int l = 0; l < 4; ++l)
          atomicAdd(&outp[(size_t)(p0 + a) * Un + k * 32 + ug * 4 + l],
                    acc[a][k * 4 + l]);
  } else {
    float* base = outp + (size_t)c * (Pn * Un);
#pragma unroll
    for (int a = 0; a < 8; ++a)
#pragma unroll
      for (int k = 0; k < 4; ++k) {
        f4 v;
#pragma unroll
        for (int l = 0; l < 4; ++l) v[l] = acc[a][k * 4 + l];
        *(f4*)&base[(size_t)(p0 + a) * Un + k * 32 + ug * 4] = v;
      }
  }
}

// ---------------------------------------------------------------------------
// Kernel D: reduce partials over chunks + bias + tanh   (partials path)
// ---------------------------------------------------------------------------
__global__ __launch_bounds__(256) void kD(const float* __restrict__ part,
                                          const float* __restrict__ bias,
                                          float* __restrict__ out) {
  const int g = blockIdx.x * 256 + threadIdx.x;  // 32768 = P*U
  const int u = g & (Un - 1);
  float a = 0.0f;
#pragma unroll 8
  for (int c = 0; c < NC; ++c) a += part[(size_t)c * (Pn * Un) + g];
  out[g] = tanhf(a + bias[u]);
}

// tanh finisher for the atomic fallback path
__global__ __launch_bounds__(256) void kD2(float* __restrict__ out,
                                           const float* __restrict__ bias) {
  const int g = blockIdx.x * 256 + threadIdx.x;
  out[g] = tanhf(out[g] + bias[g & (Un - 1)]);
}

// ---------------------------------------------------------------------------
extern "C" void kernel_launch(void* const* d_in, const int* in_sizes, int n_in,
                              void* d_out, int out_size, void* d_ws,
                              size_t ws_size, hipStream_t stream) {
  const float* in   = (const float*)d_in[0];  // [P, T]
  const float* pw   = (const float*)d_in[1];  // [P]
  const float* Kg   = (const float*)d_in[2];  // [T, U]
  const float* bias = (const float*)d_in[3];  // [U]
  const float* st   = (const float*)d_in[4];  // [P]
  float* out = (float*)d_out;                 // [P, U]
  float* ws = (float*)d_ws;

  float* Aarr = ws;                  // NC*P floats
  float* Barr = ws + NC * Pn;        // NC*P floats
  float* sinb = ws + 2 * NC * Pn;    // NC*P floats   (total 768 KB)
  float* part = ws + 262144;         // NC*P*U floats at 1 MB offset

  const size_t needPart =
      (262144 + (size_t)NC * Pn * Un) * sizeof(float);  // ~34.6 MB

  kA<<<NC, 1024, 0, stream>>>(in, pw, Aarr, Barr);
  kB<<<1, Pn, 0, stream>>>(Aarr, Barr, st, sinb);

  if (ws_size >= needPart) {
    kC<false><<<NC, 256, 0, stream>>>(in, pw, Kg, sinb, part);
    kD<<<(Pn * Un) / 256, 256, 0, stream>>>(part, bias, out);
  } else {
    hipMemsetAsync(d_out, 0, (size_t)Pn * Un * sizeof(float), stream);
    kC<true><<<NC, 256, 0, stream>>>(in, pw, Kg, sinb, out);
    kD2<<<(Pn * Un) / 256, 256, 0, stream>>>(out, bias);
  }
}